// Round 11
// baseline (401.458 us; speedup 1.0000x reference)
//
#include <hip/hip_runtime.h>
#include <hip/hip_bf16.h>

#define F_NODE 128

typedef float f32x4 __attribute__((ext_vector_type(4)));
typedef float f32x2 __attribute__((ext_vector_type(2)));

__device__ __forceinline__ float bflo(unsigned int v) {
    return __uint_as_float(v << 16);
}
__device__ __forceinline__ float bfhi(unsigned int v) {
    return __uint_as_float(v & 0xffff0000u);
}
// packed 2xbf16 atomic add (gfx950 native, fire-and-forget: no return)
__device__ __forceinline__ void atomic_pk_bf16(unsigned* addr, unsigned val) {
    asm volatile("global_atomic_pk_add_bf16 %0, %1, off"
                 :: "v"((unsigned long long)(size_t)addr), "v"(val));
}

// ---------------------------------------------------------------------------
// K0: zero cursor + zero S (all blocks) + fold weights (block 0).
//  Wnt[f][k] = W_node[k][f]; M2[k][g] = Wg@Wl_top (32x64); cvec; Wet = We^T
__global__ void k_prep(const float* __restrict__ Wn,
                       const float* __restrict__ Wgz, const float* __restrict__ Wgh,
                       const float* __restrict__ Wlz, const float* __restrict__ Wlh,
                       const float* __restrict__ bgz, const float* __restrict__ bgh,
                       const float* __restrict__ blz, const float* __restrict__ blh,
                       const float* __restrict__ We,
                       float* __restrict__ Wnt, float* __restrict__ M2,
                       float* __restrict__ cvec, float* __restrict__ Wet,
                       int* __restrict__ cursor, uint4* __restrict__ S4, int N) {
    int tid = threadIdx.x;
    int t = blockIdx.x * 256 + tid;
    int gstride = gridDim.x * 256;
    for (int j = t; j < N; j += gstride) cursor[j] = 0;
    uint4 z = make_uint4(0, 0, 0, 0);
    int nS = 4 * N;                      // 32N bf16 = 64N bytes = 4N uint4
    for (int j = t; j < nS; j += gstride) S4[j] = z;

    if (blockIdx.x != 0) return;
    for (int j = tid; j < 32 * 128; j += 256) {
        int f = j >> 7, k = j & 127;
        Wnt[j] = Wn[k * 32 + f];
    }
    for (int j = tid; j < 32 * 64; j += 256) {
        int k = j >> 6, g = j & 63, f = g & 31;
        const float* G = (g < 32) ? Wgz : Wgh;
        const float* L = (g < 32) ? Wlz : Wlh;   // top-half rows 0..31 of [64,32]
        float s = 0.f;
        for (int q = 0; q < 32; ++q) s += G[k * 32 + q] * L[q * 32 + f];
        M2[j] = s;
    }
    for (int j = tid; j < 64; j += 256) {
        int f = j & 31;
        const float* L  = (j < 32) ? Wlz : Wlh;
        const float* bg = (j < 32) ? bgz : bgh;
        const float* bl = (j < 32) ? blz : blh;
        float s = bl[f];
        for (int q = 0; q < 32; ++q) s += bg[q] * L[q * 32 + f];
        cvec[j] = s;
    }
    for (int j = tid; j < 32 * 32; j += 256) {
        int f = j >> 5, k = j & 31;
        Wet[j] = We[k * 32 + f];
    }
}

// ---------------------------------------------------------------------------
// FAT: slot = bid&1.  0 -> degree count (int atomics, fire-and-forget),
//                     1 -> edge matmul out[e] = relu(ea@We+be).w3 + b0.
__global__ __launch_bounds__(256) void k_fat(
        const int* __restrict__ row, const int* __restrict__ col,
        int* __restrict__ cursor,
        const float* __restrict__ ea, const float* __restrict__ Wet,
        const float* __restrict__ be, const float* __restrict__ Wout,
        const float* __restrict__ bout, float* __restrict__ out, int E) {
    __shared__ float sW[1024];
    __shared__ float sb[32], sw3[32];
    int bid = blockIdx.x, tid = threadIdx.x;
    int e = (bid >> 1) * 256 + tid;

    if ((bid & 1) == 0) {
        if (e < E) atomicAdd(&cursor[col[e]], 1);
        return;
    }
    for (int j = tid; j < 1024; j += 256) sW[j] = Wet[j];
    if (tid < 32) { sb[tid] = be[tid]; sw3[tid] = Wout[64 + tid]; }
    __syncthreads();
    if (e >= E) return;
    f32x4 er[8];
    const f32x4* erow = (const f32x4*)(ea + (size_t)e * 32);
    #pragma unroll
    for (int r = 0; r < 8; ++r) er[r] = __builtin_nontemporal_load(erow + r);
    float p = 0.f;
    #pragma unroll 4
    for (int f = 0; f < 32; ++f) {
        const f32x4* wf = (const f32x4*)(sW + f * 32);
        f32x4 v0 = er[0] * wf[0];
        f32x4 v1 = er[1] * wf[1];
        #pragma unroll
        for (int k = 2; k < 8; k += 2) {
            v0 += er[k] * wf[k];
            v1 += er[k + 1] * wf[k + 1];
        }
        f32x4 v = v0 + v1;
        float sfin = (v[0] + v[1]) + (v[2] + v[3]);
        p += fmaxf(sb[f] + sfin, 0.f) * sw3[f];
    }
    __builtin_nontemporal_store(p + bout[0], out + e);
}

// ---------------------------------------------------------------------------
// K2: node encoder (after deg). ysb[i][f] = bf16( rsqrt(deg+1)*relu(x@Wn+bn) )
__global__ __launch_bounds__(256) void k_enc(
        const float* __restrict__ x, const float* __restrict__ bn,
        const float* __restrict__ Wnt, const int* __restrict__ cursor,
        __hip_bfloat16* __restrict__ ysb, int N) {
    __shared__ float sx[4][128];
    int tid = threadIdx.x;
    int w = tid >> 6, l = tid & 63;
    int f = l & 31, kh = l >> 5;

    f32x4 wreg[16];
    const f32x4* wp = (const f32x4*)(Wnt + f * 128 + kh * 64);
    #pragma unroll
    for (int r = 0; r < 16; ++r) wreg[r] = wp[r];
    float bnf = bn[f];

    int stride = gridDim.x * 4;
    int i = blockIdx.x * 4 + w;
    f32x2 xv = {0.f, 0.f};
    if (i < N)
        xv = __builtin_nontemporal_load((const f32x2*)(x + (size_t)i * F_NODE) + l);

    for (; i < N; i += stride) {
        sx[w][2 * l]     = xv[0];
        sx[w][2 * l + 1] = xv[1];
        int inext = i + stride;
        if (inext < N)
            xv = __builtin_nontemporal_load(
                     (const f32x2*)(x + (size_t)inext * F_NODE) + l);

        const f32x4* sxp = (const f32x4*)(&sx[w][kh * 64]);
        f32x4 a0 = sxp[0] * wreg[0];
        f32x4 a1 = sxp[1] * wreg[1];
        f32x4 a2 = sxp[2] * wreg[2];
        f32x4 a3 = sxp[3] * wreg[3];
        #pragma unroll
        for (int r = 4; r < 16; r += 4) {
            a0 += sxp[r]     * wreg[r];
            a1 += sxp[r + 1] * wreg[r + 1];
            a2 += sxp[r + 2] * wreg[r + 2];
            a3 += sxp[r + 3] * wreg[r + 3];
        }
        f32x4 av = (a0 + a1) + (a2 + a3);
        float acc = (av[0] + av[1]) + (av[2] + av[3]);
        acc += __shfl_xor(acc, 32);
        float d = rsqrtf((float)cursor[i] + 1.0f);
        acc = d * fmaxf(acc + bnf, 0.f);
        if (l < 32)
            ysb[(size_t)i * 32 + f] = __float2bfloat16(acc);
    }
}

// ---------------------------------------------------------------------------
// K3: direct scatter-add. Task t: edge e = t>>4, feature-pair fp = t&15.
// 16 lanes cover one edge's 32 bf16 feats -> ONE 64B line per edge.
// pk atomics are no-return (store-like): no latency to hide.
__global__ __launch_bounds__(256) void k_scatter(
        const int* __restrict__ row, const int* __restrict__ col,
        const unsigned short* __restrict__ ysb, unsigned* __restrict__ S32,
        long long T) {
    long long t = (long long)blockIdx.x * 256 + threadIdx.x;
    long long stride = (long long)gridDim.x * 256;
    for (; t < T; t += stride) {
        int e  = (int)(t >> 4);
        int fp = (int)(t & 15);
        int r = row[e], c = col[e];
        unsigned val = *(const unsigned*)(ysb + (size_t)r * 32 + 2 * fp);
        atomic_pk_bf16(S32 + (size_t)c * 16 + fp, val);
    }
}

// ---------------------------------------------------------------------------
// K4: node finalize. Wave per node: total = S[c] + ys[c] (self-loop),
// a = dc*(total@M2)+cvec, Z/Ht split, hr/hc scalars. M2 col in registers.
__global__ __launch_bounds__(256) void k_fin(
        const int* __restrict__ cursor, const unsigned short* __restrict__ Sb,
        const unsigned short* __restrict__ ysb,
        const float* __restrict__ M2, const float* __restrict__ cvec,
        const float* __restrict__ Wout,
        float* __restrict__ hr, float* __restrict__ hc, int N) {
    int tid = threadIdx.x;
    int w = tid >> 6, l = tid & 63;
    int q = l & 7;

    float mcol[32];
    #pragma unroll
    for (int k = 0; k < 32; ++k) mcol[k] = M2[k * 64 + l];
    float cvl = cvec[l];
    float w0l = Wout[l & 31];
    float w1l = Wout[32 + (l & 31)];

    int stride = gridDim.x * 4;
    for (int c = blockIdx.x * 4 + w; c < N; c += stride) {
        float dc = rsqrtf((float)cursor[c] + 1.0f);
        uint2 s1 = *(const uint2*)(Sb  + (size_t)c * 32 + 4 * q);
        uint2 s2 = *(const uint2*)(ysb + (size_t)c * 32 + 4 * q);
        float a0 = bflo(s1.x) + bflo(s2.x), a1 = bfhi(s1.x) + bfhi(s2.x);
        float a2 = bflo(s1.y) + bflo(s2.y), a3 = bfhi(s1.y) + bfhi(s2.y);

        float acc = 0.f;
        #pragma unroll
        for (int kq = 0; kq < 8; ++kq) {   // shfl source lane kq has q==kq
            float s0 = __shfl(a0, kq), t1 = __shfl(a1, kq);
            float t2 = __shfl(a2, kq), t3 = __shfl(a3, kq);
            acc += s0 * mcol[4 * kq]     + t1 * mcol[4 * kq + 1]
                 + t2 * mcol[4 * kq + 2] + t3 * mcol[4 * kq + 3];
        }
        float a = dc * acc + cvl;
        float v = (l < 32) ? (1.f / (1.f + __expf(-a))) : tanhf(a);
        float o = __shfl_xor(v, 32);
        float h = (1.f - v) * o;             // valid on lanes l<32
        float pr = h * w0l;
        float pc = h * w1l;
        #pragma unroll
        for (int m = 16; m >= 1; m >>= 1) {
            pr += __shfl_xor(pr, m);
            pc += __shfl_xor(pc, m);
        }
        if (l == 0) { hr[c] = pr; hc[c] = pc; }
    }
}

// ---------------------------------------------------------------------------
// K5: out[e] += hr[row[e]] + hc[col[e]]   (hr/hc 400KB each: L2/L3-resident)
__global__ __launch_bounds__(256) void k_edge_add(
        const int* __restrict__ row, const int* __restrict__ col,
        const float* __restrict__ hr, const float* __restrict__ hc,
        float* __restrict__ out, int E) {
    int e = blockIdx.x * 256 + threadIdx.x;
    if (e < E) out[e] += hr[row[e]] + hc[col[e]];
}

// ---------------------------------------------------------------------------
extern "C" void kernel_launch(void* const* d_in, const int* in_sizes, int n_in,
                              void* d_out, int out_size, void* d_ws, size_t ws_size,
                              hipStream_t stream) {
    const float* x    = (const float*)d_in[0];
    const int*   ei   = (const int*)  d_in[1];
    const float* ea   = (const float*)d_in[2];
    const float* Wn   = (const float*)d_in[3];
    const float* bn   = (const float*)d_in[4];
    const float* We   = (const float*)d_in[5];
    const float* be   = (const float*)d_in[6];
    const float* Wgz  = (const float*)d_in[7];
    const float* bgz  = (const float*)d_in[8];
    // d_in[9..10] = Wg_r, bg_r : dead (h0 == 0)
    const float* Wgh  = (const float*)d_in[11];
    const float* bgh  = (const float*)d_in[12];
    const float* Wlz  = (const float*)d_in[13];
    const float* blz  = (const float*)d_in[14];
    // d_in[15..16] = Wl_r, bl_r : dead
    const float* Wlh  = (const float*)d_in[17];
    const float* blh  = (const float*)d_in[18];
    const float* Wout = (const float*)d_in[19];
    const float* bout = (const float*)d_in[20];

    int N = in_sizes[0] / F_NODE;
    int E = in_sizes[1] / 2;
    const int* row = ei;
    const int* col = ei + E;

    // ws layout (float units):
    // ysb(bf16)[32N]=16N | Sb(bf16)[32N]=16N | Wnt[4096] | M2[2048]
    // | Wet[1024] | cvec[64] | hr[N] | hc[N] | cursor(int)[N]
    float* ws    = (float*)d_ws;
    __hip_bfloat16* ysb = (__hip_bfloat16*)ws;
    __hip_bfloat16* Sb  = (__hip_bfloat16*)(ws + (size_t)16 * N);
    float* Wnt   = ws + (size_t)32 * N;
    float* M2    = Wnt + 4096;
    float* Wet   = M2 + 2048;
    float* cvec  = Wet + 1024;
    float* hr    = cvec + 64;
    float* hc    = hr + N;
    int*   cursor= (int*)(hc + N);
    float* out   = (float*)d_out;

    k_prep<<<400, 256, 0, stream>>>(Wn, Wgz, Wgh, Wlz, Wlh, bgz, bgh, blz, blh,
                                    We, Wnt, M2, cvec, Wet, cursor,
                                    (uint4*)Sb, N);
    int eb = (E + 255) / 256;
    k_fat<<<2 * eb, 256, 0, stream>>>(row, col, cursor, ea, Wet, be, Wout,
                                      bout, out, E);
    k_enc<<<768, 256, 0, stream>>>(x, bn, Wnt, cursor, ysb, N);
    long long T = (long long)E * 16;
    k_scatter<<<8192, 256, 0, stream>>>(row, col, (const unsigned short*)ysb,
                                        (unsigned*)Sb, T);
    k_fin<<<2048, 256, 0, stream>>>(cursor, (const unsigned short*)Sb,
                                    (const unsigned short*)ysb,
                                    M2, cvec, Wout, hr, hc, N);
    k_edge_add<<<eb, 256, 0, stream>>>(row, col, hr, hc, out, E);
}

// Round 12
// 246.097 us; speedup vs baseline: 1.6313x; 1.6313x over previous
//
#include <hip/hip_runtime.h>
#include <hip/hip_bf16.h>

#define F_NODE 128
#define BINCAP 64

typedef float f32x4 __attribute__((ext_vector_type(4)));
typedef float f32x2 __attribute__((ext_vector_type(2)));

__device__ __forceinline__ float bflo(unsigned int v) {
    return __uint_as_float(v << 16);
}
__device__ __forceinline__ float bfhi(unsigned int v) {
    return __uint_as_float(v & 0xffff0000u);
}

// ---------------------------------------------------------------------------
// K0: zero cursor (all blocks) + fold weights (block 0).
//  Wnt[f][k] = W_node[k][f]; M2[k][g] = Wg@Wl_top (32x64); cvec; Wet = We^T
__global__ void k_prep(const float* __restrict__ Wn,
                       const float* __restrict__ Wgz, const float* __restrict__ Wgh,
                       const float* __restrict__ Wlz, const float* __restrict__ Wlh,
                       const float* __restrict__ bgz, const float* __restrict__ bgh,
                       const float* __restrict__ blz, const float* __restrict__ blh,
                       const float* __restrict__ We,
                       float* __restrict__ Wnt, float* __restrict__ M2,
                       float* __restrict__ cvec, float* __restrict__ Wet,
                       int* __restrict__ cursor, int N) {
    int tid = threadIdx.x;
    int t = blockIdx.x * 256 + tid;
    int gstride = gridDim.x * 256;
    for (int j = t; j < N; j += gstride) cursor[j] = 0;

    if (blockIdx.x != 0) return;
    for (int j = tid; j < 32 * 128; j += 256) {
        int f = j >> 7, k = j & 127;
        Wnt[j] = Wn[k * 32 + f];
    }
    for (int j = tid; j < 32 * 64; j += 256) {
        int k = j >> 6, g = j & 63, f = g & 31;
        const float* G = (g < 32) ? Wgz : Wgh;
        const float* L = (g < 32) ? Wlz : Wlh;   // top-half rows 0..31 of [64,32]
        float s = 0.f;
        for (int q = 0; q < 32; ++q) s += G[k * 32 + q] * L[q * 32 + f];
        M2[j] = s;
    }
    for (int j = tid; j < 64; j += 256) {
        int f = j & 31;
        const float* L  = (j < 32) ? Wlz : Wlh;
        const float* bg = (j < 32) ? bgz : bgh;
        const float* bl = (j < 32) ? blz : blh;
        float s = bl[f];
        for (int q = 0; q < 32; ++q) s += bg[q] * L[q * 32 + f];
        cvec[j] = s;
    }
    for (int j = tid; j < 32 * 32; j += 256) {
        int f = j >> 5, k = j & 31;
        Wet[j] = We[k * 32 + f];
    }
}

// ---------------------------------------------------------------------------
// K1: FUSED per-edge kernel — every thread owns one edge and does BOTH:
//   (a) bin-fill: pos = atomicAdd(cursor[col]); bin[col*64+pos] = row
//   (b) edge matmul: out[e] = relu(ea@We+be).w3 + b0
// The ~70 VALU ops of (b) hide the atomic/store latency of (a): no role
// imbalance, no straggler fill blocks (r4's split: fill-alone 137us floor).
// All loads/stores REGULAR (NT correlated with every fat regression r8-r11).
__global__ __launch_bounds__(256) void k_fatm(
        const int* __restrict__ row, const int* __restrict__ col,
        int* __restrict__ cursor, int* __restrict__ bin,
        const float* __restrict__ ea, const float* __restrict__ Wet,
        const float* __restrict__ be, const float* __restrict__ Wout,
        const float* __restrict__ bout, float* __restrict__ out, int E) {
    __shared__ float sW[1024];
    __shared__ float sb[32], sw3[32];
    int tid = threadIdx.x;
    for (int j = tid; j < 1024; j += 256) sW[j] = Wet[j];
    if (tid < 32) { sb[tid] = be[tid]; sw3[tid] = Wout[64 + tid]; }
    __syncthreads();

    int e = blockIdx.x * 256 + tid;
    if (e >= E) return;

    int c = col[e];
    int r = row[e];
    const f32x4* erow = (const f32x4*)(ea + (size_t)e * 32);
    f32x4 er[8];
    #pragma unroll
    for (int k = 0; k < 8; ++k) er[k] = erow[k];

    // issue the atomic early: its result (pos) is only needed after the MM,
    // so the entire matmul hides the round-trip.
    int pos = atomicAdd(&cursor[c], 1);

    float p = 0.f;
    #pragma unroll 4
    for (int f = 0; f < 32; ++f) {
        const f32x4* wf = (const f32x4*)(sW + f * 32);
        f32x4 v0 = er[0] * wf[0];
        f32x4 v1 = er[1] * wf[1];
        #pragma unroll
        for (int k = 2; k < 8; k += 2) {
            v0 += er[k] * wf[k];
            v1 += er[k + 1] * wf[k + 1];
        }
        f32x4 v = v0 + v1;
        float sfin = (v[0] + v[1]) + (v[2] + v[3]);
        p += fmaxf(sb[f] + sfin, 0.f) * sw3[f];
    }
    out[e] = p + bout[0];
    if (pos < BINCAP) bin[((size_t)c << 6) + pos] = r;
}

// ---------------------------------------------------------------------------
// K2: node encoder (after fatm -> degrees known). Wave-per-node; weight
// column in 16 f32x4 registers; x staged wave-private in LDS. PRE-SCALED:
//   ysb[i][f] = bf16( rsqrt(deg_i+1) * relu(x_i @ Wn + bn)[f] )
__global__ __launch_bounds__(256) void k_enc(
        const float* __restrict__ x, const float* __restrict__ bn,
        const float* __restrict__ Wnt, const int* __restrict__ cursor,
        __hip_bfloat16* __restrict__ ysb, int N) {
    __shared__ float sx[4][128];
    int tid = threadIdx.x;
    int w = tid >> 6, l = tid & 63;
    int f = l & 31, kh = l >> 5;

    f32x4 wreg[16];
    const f32x4* wp = (const f32x4*)(Wnt + f * 128 + kh * 64);
    #pragma unroll
    for (int r = 0; r < 16; ++r) wreg[r] = wp[r];
    float bnf = bn[f];

    int stride = gridDim.x * 4;
    int i = blockIdx.x * 4 + w;
    f32x2 xv = {0.f, 0.f};
    if (i < N) xv = ((const f32x2*)(x + (size_t)i * F_NODE))[l];

    for (; i < N; i += stride) {
        sx[w][2 * l]     = xv[0];
        sx[w][2 * l + 1] = xv[1];
        int inext = i + stride;
        if (inext < N)
            xv = ((const f32x2*)(x + (size_t)inext * F_NODE))[l];

        const f32x4* sxp = (const f32x4*)(&sx[w][kh * 64]);
        f32x4 a0 = sxp[0] * wreg[0];
        f32x4 a1 = sxp[1] * wreg[1];
        f32x4 a2 = sxp[2] * wreg[2];
        f32x4 a3 = sxp[3] * wreg[3];
        #pragma unroll
        for (int r = 4; r < 16; r += 4) {
            a0 += sxp[r]     * wreg[r];
            a1 += sxp[r + 1] * wreg[r + 1];
            a2 += sxp[r + 2] * wreg[r + 2];
            a3 += sxp[r + 3] * wreg[r + 3];
        }
        f32x4 av = (a0 + a1) + (a2 + a3);
        float acc = (av[0] + av[1]) + (av[2] + av[3]);
        acc += __shfl_xor(acc, 32);
        float d = rsqrtf((float)cursor[i] + 1.0f);
        acc = d * fmaxf(acc + bnf, 0.f);
        if (l < 32)
            ysb[(size_t)i * 32 + f] = __float2bfloat16(acc);
    }
}

// ---------------------------------------------------------------------------
// K3: persistent wave-per-node gather. M2 column l in 32 registers.
// Lane (q=l&7, s=l>>3): uint2 = 4 bf16/lane, 8 lanes/edge -> 8 edges in
// flight. Epilogue matvec via static-index unrolled shfl; Z/Ht; hr/hc.
__global__ __launch_bounds__(256) void k_gather(
        const int* __restrict__ cursor, const int* __restrict__ bin,
        const unsigned short* __restrict__ ysb,
        const float* __restrict__ M2, const float* __restrict__ cvec,
        const float* __restrict__ Wout,
        float* __restrict__ hr, float* __restrict__ hc, int N) {
    int tid = threadIdx.x;
    int w = tid >> 6, l = tid & 63;
    int q = l & 7, s = l >> 3;

    float mcol[32];
    #pragma unroll
    for (int k = 0; k < 32; ++k) mcol[k] = M2[k * 64 + l];
    float cvl = cvec[l];
    float w0l = Wout[l & 31];
    float w1l = Wout[32 + (l & 31)];

    int stride = gridDim.x * 4;
    for (int c = blockIdx.x * 4 + w; c < N; c += stride) {
        int truec = cursor[c];
        float dc = rsqrtf((float)truec + 1.0f);
        int cnt = truec < BINCAP ? truec : BINCAP;
        const int* bp = bin + ((size_t)c << 6);
        int myr = (l < cnt) ? bp[l] : 0;

        float a0 = 0.f, a1 = 0.f, a2 = 0.f, a3 = 0.f;
        uint2 sv = *(const uint2*)(ysb + (size_t)c * 32 + 4 * q);
        if (s == 0) {
            a0 = bflo(sv.x); a1 = bfhi(sv.x);
            a2 = bflo(sv.y); a3 = bfhi(sv.y);
        }
        for (int j = 0; j < cnt; j += 8) {
            int jj = j + s;
            if (jj < cnt) {
                int r = __shfl(myr, jj);
                uint2 v = *(const uint2*)(ysb + (size_t)r * 32 + 4 * q);
                a0 += bflo(v.x); a1 += bfhi(v.x);
                a2 += bflo(v.y); a3 += bfhi(v.y);
            }
        }
        a0 += __shfl_xor(a0, 8);  a1 += __shfl_xor(a1, 8);
        a2 += __shfl_xor(a2, 8);  a3 += __shfl_xor(a3, 8);
        a0 += __shfl_xor(a0, 16); a1 += __shfl_xor(a1, 16);
        a2 += __shfl_xor(a2, 16); a3 += __shfl_xor(a3, 16);
        a0 += __shfl_xor(a0, 32); a1 += __shfl_xor(a1, 32);
        a2 += __shfl_xor(a2, 32); a3 += __shfl_xor(a3, 32);
        // lane with q=kq now holds S[4kq..4kq+3] in a0..a3

        float acc = 0.f;
        #pragma unroll
        for (int kq = 0; kq < 8; ++kq) {
            float s0 = __shfl(a0, kq), t1 = __shfl(a1, kq);
            float t2 = __shfl(a2, kq), t3 = __shfl(a3, kq);
            acc += s0 * mcol[4 * kq]     + t1 * mcol[4 * kq + 1]
                 + t2 * mcol[4 * kq + 2] + t3 * mcol[4 * kq + 3];
        }
        float a = dc * acc + cvl;
        float v = (l < 32) ? (1.f / (1.f + __expf(-a))) : tanhf(a);
        float o = __shfl_xor(v, 32);
        float h = (1.f - v) * o;             // valid on lanes l<32
        float pr = h * w0l;
        float pc = h * w1l;
        #pragma unroll
        for (int m = 16; m >= 1; m >>= 1) {
            pr += __shfl_xor(pr, m);
            pc += __shfl_xor(pc, m);
        }
        if (l == 0) { hr[c] = pr; hc[c] = pc; }
    }
}

// ---------------------------------------------------------------------------
// K4: out[e] += hr[row[e]] + hc[col[e]]   (hr/hc 400KB each: L2/L3-resident)
__global__ __launch_bounds__(256) void k_edge_add(
        const int* __restrict__ row, const int* __restrict__ col,
        const float* __restrict__ hr, const float* __restrict__ hc,
        float* __restrict__ out, int E) {
    int e = blockIdx.x * 256 + threadIdx.x;
    if (e < E) out[e] += hr[row[e]] + hc[col[e]];
}

// ---------------------------------------------------------------------------
extern "C" void kernel_launch(void* const* d_in, const int* in_sizes, int n_in,
                              void* d_out, int out_size, void* d_ws, size_t ws_size,
                              hipStream_t stream) {
    const float* x    = (const float*)d_in[0];
    const int*   ei   = (const int*)  d_in[1];
    const float* ea   = (const float*)d_in[2];
    const float* Wn   = (const float*)d_in[3];
    const float* bn   = (const float*)d_in[4];
    const float* We   = (const float*)d_in[5];
    const float* be   = (const float*)d_in[6];
    const float* Wgz  = (const float*)d_in[7];
    const float* bgz  = (const float*)d_in[8];
    // d_in[9..10] = Wg_r, bg_r : dead (h0 == 0)
    const float* Wgh  = (const float*)d_in[11];
    const float* bgh  = (const float*)d_in[12];
    const float* Wlz  = (const float*)d_in[13];
    const float* blz  = (const float*)d_in[14];
    // d_in[15..16] = Wl_r, bl_r : dead
    const float* Wlh  = (const float*)d_in[17];
    const float* blh  = (const float*)d_in[18];
    const float* Wout = (const float*)d_in[19];
    const float* bout = (const float*)d_in[20];

    int N = in_sizes[0] / F_NODE;
    int E = in_sizes[1] / 2;
    const int* row = ei;
    const int* col = ei + E;

    // ws layout (float units):
    // ysb(bf16)[32N]=16N | bin(int)[64N] | Wnt[4096] | M2[2048] | Wet[1024]
    // | cvec[64] | hr[N] | hc[N] | cursor(int)[N]
    float* ws    = (float*)d_ws;
    __hip_bfloat16* ysb = (__hip_bfloat16*)ws;
    int*   bin   = (int*)(ws + (size_t)16 * N);
    float* Wnt   = ws + (size_t)80 * N;
    float* M2    = Wnt + 4096;
    float* Wet   = M2 + 2048;
    float* cvec  = Wet + 1024;
    float* hr    = cvec + 64;
    float* hc    = hr + N;
    int*   cursor= (int*)(hc + N);
    float* out   = (float*)d_out;

    k_prep<<<400, 256, 0, stream>>>(Wn, Wgz, Wgh, Wlz, Wlh, bgz, bgh, blz, blh,
                                    We, Wnt, M2, cvec, Wet, cursor, N);
    int eb = (E + 255) / 256;
    k_fatm<<<eb, 256, 0, stream>>>(row, col, cursor, bin, ea, Wet, be, Wout,
                                   bout, out, E);
    k_enc<<<768, 256, 0, stream>>>(x, bn, Wnt, cursor, ysb, N);
    k_gather<<<2048, 256, 0, stream>>>(cursor, bin, (const unsigned short*)ysb,
                                       M2, cvec, Wout, hr, hc, N);
    k_edge_add<<<eb, 256, 0, stream>>>(row, col, hr, hc, out, E);
}

// Round 13
// 231.493 us; speedup vs baseline: 1.7342x; 1.0631x over previous
//
#include <hip/hip_runtime.h>
#include <hip/hip_bf16.h>

#define F_NODE 128
#define BINCAP 64
#define ENCB 768

typedef float f32x4 __attribute__((ext_vector_type(4)));
typedef float f32x2 __attribute__((ext_vector_type(2)));

__device__ __forceinline__ float bflo(unsigned int v) {
    return __uint_as_float(v << 16);
}
__device__ __forceinline__ float bfhi(unsigned int v) {
    return __uint_as_float(v & 0xffff0000u);
}
__device__ __forceinline__ unsigned bfpack(float f) {
    __hip_bfloat16 b = __float2bfloat16(f);
    return (unsigned)*reinterpret_cast<unsigned short*>(&b);
}

// ---------------------------------------------------------------------------
// K0: zero cursor (all blocks) + fold weights (block 0).
//  Wnp[k2][f] = pack2bf16(Wn[2k2][f], Wn[2k2+1][f])   (64x32 uints)
//  M2[k][g]  = Wg_sel @ Wl_top  (32x64; g<32 -> z)
//  cvec[g]   = bg@Wl_top + bl;  Wet[f][k] = We^T
__global__ void k_prep(const float* __restrict__ Wn,
                       const float* __restrict__ Wgz, const float* __restrict__ Wgh,
                       const float* __restrict__ Wlz, const float* __restrict__ Wlh,
                       const float* __restrict__ bgz, const float* __restrict__ bgh,
                       const float* __restrict__ blz, const float* __restrict__ blh,
                       const float* __restrict__ We,
                       unsigned* __restrict__ Wnp, float* __restrict__ M2,
                       float* __restrict__ cvec, float* __restrict__ Wet,
                       int* __restrict__ cursor, int N) {
    int tid = threadIdx.x;
    int t = blockIdx.x * 256 + tid;
    int gstride = gridDim.x * 256;
    for (int j = t; j < N; j += gstride) cursor[j] = 0;

    if (blockIdx.x != 0) return;
    for (int j = tid; j < 64 * 32; j += 256) {
        int k2 = j >> 5, f = j & 31;
        unsigned lo = bfpack(Wn[(2 * k2) * 32 + f]);
        unsigned hi = bfpack(Wn[(2 * k2 + 1) * 32 + f]);
        Wnp[j] = lo | (hi << 16);
    }
    for (int j = tid; j < 32 * 64; j += 256) {
        int k = j >> 6, g = j & 63, f = g & 31;
        const float* G = (g < 32) ? Wgz : Wgh;
        const float* L = (g < 32) ? Wlz : Wlh;   // top-half rows 0..31 of [64,32]
        float s = 0.f;
        for (int q = 0; q < 32; ++q) s += G[k * 32 + q] * L[q * 32 + f];
        M2[j] = s;
    }
    for (int j = tid; j < 64; j += 256) {
        int f = j & 31;
        const float* L  = (j < 32) ? Wlz : Wlh;
        const float* bg = (j < 32) ? bgz : bgh;
        const float* bl = (j < 32) ? blz : blh;
        float s = bl[f];
        for (int q = 0; q < 32; ++q) s += bg[q] * L[q * 32 + f];
        cvec[j] = s;
    }
    for (int j = tid; j < 32 * 32; j += 256) {
        int f = j >> 5, k = j & 31;
        Wet[j] = We[k * 32 + f];
    }
}

// ---------------------------------------------------------------------------
// K1: FAT kernel.
//  bid < ENCB : node encoder role — 2 nodes/wave, W_node as packed bf16 in
//     LDS (8KB; keeps VGPR ~40 and LDS ~12.6KB so edge blocks keep full
//     occupancy — fixes r5's VGPR and r7's LDS mistakes). UNSCALED ysb.
//  bid >= ENCB: fused per-edge (r12-proven, byte-identical path):
//     pos = atomicAdd(cursor[col]) issued early; full edge matmul hides it;
//     bin store last.  out[e] = relu(ea@We+be).w3 + b0.
__global__ __launch_bounds__(256) void k_fatm(
        const int* __restrict__ row, const int* __restrict__ col,
        int* __restrict__ cursor, int* __restrict__ bin,
        const float* __restrict__ ea, const float* __restrict__ Wet,
        const float* __restrict__ be, const float* __restrict__ Wout,
        const float* __restrict__ bout, float* __restrict__ out,
        const float* __restrict__ x, const float* __restrict__ bn,
        const unsigned* __restrict__ Wnp, __hip_bfloat16* __restrict__ ysb,
        int E, int N) {
    __shared__ unsigned smem[3104];  // enc: Wnp 2048 | sx 1024 | sbn 32 ; MM: 1088
    int bid = blockIdx.x, tid = threadIdx.x;

    if (bid < ENCB) {
        // ---- node encoder role ----
        unsigned* sWnp = smem;
        float*    sx   = (float*)(smem + 2048);
        float*    sbn  = (float*)(smem + 3072);
        for (int j = tid; j < 2048; j += 256) sWnp[j] = Wnp[j];
        if (tid < 32) sbn[tid] = bn[tid];
        __syncthreads();

        int w = tid >> 6, l = tid & 63;
        int f = l & 31, h2 = l >> 5;
        float* sxw = sx + w * 256 + h2 * 128;

        int NP = (N + 1) >> 1;
        int stride = ENCB * 4;
        for (int p = bid * 4 + w; p < NP; p += stride) {
            int node = 2 * p + h2;
            int nd = node < N ? node : N - 1;
            ((f32x4*)sxw)[f] = ((const f32x4*)(x + (size_t)nd * F_NODE))[f];
            // wave-private staging: no barrier needed
            float acc = sbn[f];
            #pragma unroll 8
            for (int k2 = 0; k2 < 64; ++k2) {
                unsigned wv = sWnp[k2 * 32 + f];
                acc += sxw[2 * k2] * bflo(wv) + sxw[2 * k2 + 1] * bfhi(wv);
            }
            if (node < N)
                ysb[(size_t)node * 32 + f] = __float2bfloat16(fmaxf(acc, 0.f));
        }
        return;
    }

    // ---- fused fill + edge matmul (one edge per thread) ----
    float* sW  = (float*)smem;
    float* sb  = (float*)(smem + 1024);
    float* sw3 = (float*)(smem + 1056);
    for (int j = tid; j < 1024; j += 256) sW[j] = Wet[j];
    if (tid < 32) { sb[tid] = be[tid]; sw3[tid] = Wout[64 + tid]; }
    __syncthreads();

    int e = (bid - ENCB) * 256 + tid;
    if (e >= E) return;

    int c = col[e];
    int r = row[e];
    const f32x4* erow = (const f32x4*)(ea + (size_t)e * 32);
    f32x4 er[8];
    #pragma unroll
    for (int k = 0; k < 8; ++k) er[k] = erow[k];

    int pos = atomicAdd(&cursor[c], 1);

    float p = 0.f;
    #pragma unroll 4
    for (int f = 0; f < 32; ++f) {
        const f32x4* wf = (const f32x4*)(sW + f * 32);
        f32x4 v0 = er[0] * wf[0];
        f32x4 v1 = er[1] * wf[1];
        #pragma unroll
        for (int k = 2; k < 8; k += 2) {
            v0 += er[k] * wf[k];
            v1 += er[k + 1] * wf[k + 1];
        }
        f32x4 v = v0 + v1;
        float sfin = (v[0] + v[1]) + (v[2] + v[3]);
        p += fmaxf(sb[f] + sfin, 0.f) * sw3[f];
    }
    out[e] = p + bout[0];
    if (pos < BINCAP) bin[((size_t)c << 6) + pos] = r;
}

// ---------------------------------------------------------------------------
// K2: in-place scale  ysb[i][:] *= rsqrt(deg_i + 1)  (row = 32 bf16 = 4 uint4)
__global__ __launch_bounds__(256) void k_scale(
        uint4* __restrict__ ysb4, const int* __restrict__ cursor, int N) {
    int t = blockIdx.x * 256 + threadIdx.x;
    if (t >= N * 4) return;
    float d = rsqrtf((float)cursor[t >> 2] + 1.0f);
    uint4 v = ysb4[t];
    unsigned in[4] = {v.x, v.y, v.z, v.w};
    unsigned r[4];
    #pragma unroll
    for (int j = 0; j < 4; ++j) {
        unsigned lo = bfpack(bflo(in[j]) * d);
        unsigned hi = bfpack(bfhi(in[j]) * d);
        r[j] = lo | (hi << 16);
    }
    ysb4[t] = make_uint4(r[0], r[1], r[2], r[3]);
}

// ---------------------------------------------------------------------------
// K3: persistent wave-per-node gather. M2 column l in 32 registers.
// Lane (q=l&7, s=l>>3): uint2 = 4 bf16/lane, 8 lanes/edge -> 8 edges in
// flight. Epilogue matvec via static-index unrolled shfl; Z/Ht; hr/hc.
__global__ __launch_bounds__(256) void k_gather(
        const int* __restrict__ cursor, const int* __restrict__ bin,
        const unsigned short* __restrict__ ysb,
        const float* __restrict__ M2, const float* __restrict__ cvec,
        const float* __restrict__ Wout,
        float* __restrict__ hr, float* __restrict__ hc, int N) {
    int tid = threadIdx.x;
    int w = tid >> 6, l = tid & 63;
    int q = l & 7, s = l >> 3;

    float mcol[32];
    #pragma unroll
    for (int k = 0; k < 32; ++k) mcol[k] = M2[k * 64 + l];
    float cvl = cvec[l];
    float w0l = Wout[l & 31];
    float w1l = Wout[32 + (l & 31)];

    int stride = gridDim.x * 4;
    for (int c = blockIdx.x * 4 + w; c < N; c += stride) {
        int truec = cursor[c];
        float dc = rsqrtf((float)truec + 1.0f);
        int cnt = truec < BINCAP ? truec : BINCAP;
        const int* bp = bin + ((size_t)c << 6);
        int myr = (l < cnt) ? bp[l] : 0;

        float a0 = 0.f, a1 = 0.f, a2 = 0.f, a3 = 0.f;
        uint2 sv = *(const uint2*)(ysb + (size_t)c * 32 + 4 * q);
        if (s == 0) {
            a0 = bflo(sv.x); a1 = bfhi(sv.x);
            a2 = bflo(sv.y); a3 = bfhi(sv.y);
        }
        for (int j = 0; j < cnt; j += 8) {
            int jj = j + s;
            if (jj < cnt) {
                int r = __shfl(myr, jj);
                uint2 v = *(const uint2*)(ysb + (size_t)r * 32 + 4 * q);
                a0 += bflo(v.x); a1 += bfhi(v.x);
                a2 += bflo(v.y); a3 += bfhi(v.y);
            }
        }
        a0 += __shfl_xor(a0, 8);  a1 += __shfl_xor(a1, 8);
        a2 += __shfl_xor(a2, 8);  a3 += __shfl_xor(a3, 8);
        a0 += __shfl_xor(a0, 16); a1 += __shfl_xor(a1, 16);
        a2 += __shfl_xor(a2, 16); a3 += __shfl_xor(a3, 16);
        a0 += __shfl_xor(a0, 32); a1 += __shfl_xor(a1, 32);
        a2 += __shfl_xor(a2, 32); a3 += __shfl_xor(a3, 32);
        // lane with q=kq now holds S[4kq..4kq+3] in a0..a3

        float acc = 0.f;
        #pragma unroll
        for (int kq = 0; kq < 8; ++kq) {
            float s0 = __shfl(a0, kq), t1 = __shfl(a1, kq);
            float t2 = __shfl(a2, kq), t3 = __shfl(a3, kq);
            acc += s0 * mcol[4 * kq]     + t1 * mcol[4 * kq + 1]
                 + t2 * mcol[4 * kq + 2] + t3 * mcol[4 * kq + 3];
        }
        float a = dc * acc + cvl;
        float v = (l < 32) ? (1.f / (1.f + __expf(-a))) : tanhf(a);
        float o = __shfl_xor(v, 32);
        float h = (1.f - v) * o;             // valid on lanes l<32
        float pr = h * w0l;
        float pc = h * w1l;
        #pragma unroll
        for (int m = 16; m >= 1; m >>= 1) {
            pr += __shfl_xor(pr, m);
            pc += __shfl_xor(pc, m);
        }
        if (l == 0) { hr[c] = pr; hc[c] = pc; }
    }
}

// ---------------------------------------------------------------------------
// K4: out[e] += hr[row[e]] + hc[col[e]]   (hr/hc 400KB each: L2/L3-resident)
__global__ __launch_bounds__(256) void k_edge_add(
        const int* __restrict__ row, const int* __restrict__ col,
        const float* __restrict__ hr, const float* __restrict__ hc,
        float* __restrict__ out, int E) {
    int e = blockIdx.x * 256 + threadIdx.x;
    if (e < E) out[e] += hr[row[e]] + hc[col[e]];
}

// ---------------------------------------------------------------------------
extern "C" void kernel_launch(void* const* d_in, const int* in_sizes, int n_in,
                              void* d_out, int out_size, void* d_ws, size_t ws_size,
                              hipStream_t stream) {
    const float* x    = (const float*)d_in[0];
    const int*   ei   = (const int*)  d_in[1];
    const float* ea   = (const float*)d_in[2];
    const float* Wn   = (const float*)d_in[3];
    const float* bn   = (const float*)d_in[4];
    const float* We   = (const float*)d_in[5];
    const float* be   = (const float*)d_in[6];
    const float* Wgz  = (const float*)d_in[7];
    const float* bgz  = (const float*)d_in[8];
    // d_in[9..10] = Wg_r, bg_r : dead (h0 == 0)
    const float* Wgh  = (const float*)d_in[11];
    const float* bgh  = (const float*)d_in[12];
    const float* Wlz  = (const float*)d_in[13];
    const float* blz  = (const float*)d_in[14];
    // d_in[15..16] = Wl_r, bl_r : dead
    const float* Wlh  = (const float*)d_in[17];
    const float* blh  = (const float*)d_in[18];
    const float* Wout = (const float*)d_in[19];
    const float* bout = (const float*)d_in[20];

    int N = in_sizes[0] / F_NODE;
    int E = in_sizes[1] / 2;
    const int* row = ei;
    const int* col = ei + E;

    // ws layout (float units):
    // ysb(bf16)[32N]=16N | bin(int)[64N] | Wnp(uint)[2048] | M2[2048]
    // | Wet[1024] | cvec[64] | hr[N] | hc[N] | cursor(int)[N]
    float* ws    = (float*)d_ws;
    __hip_bfloat16* ysb = (__hip_bfloat16*)ws;
    int*   bin   = (int*)(ws + (size_t)16 * N);
    unsigned* Wnp= (unsigned*)(ws + (size_t)80 * N);
    float* M2    = ws + (size_t)80 * N + 2048;
    float* Wet   = M2 + 2048;
    float* cvec  = Wet + 1024;
    float* hr    = cvec + 64;
    float* hc    = hr + N;
    int*   cursor= (int*)(hc + N);
    float* out   = (float*)d_out;

    k_prep<<<400, 256, 0, stream>>>(Wn, Wgz, Wgh, Wlz, Wlh, bgz, bgh, blz, blh,
                                    We, Wnp, M2, cvec, Wet, cursor, N);
    int eb = (E + 255) / 256;
    k_fatm<<<ENCB + eb, 256, 0, stream>>>(row, col, cursor, bin, ea, Wet, be,
                                          Wout, bout, out, x, bn, Wnp, ysb,
                                          E, N);
    k_scale<<<(4 * N + 255) / 256, 256, 0, stream>>>((uint4*)ysb, cursor, N);
    k_gather<<<8192, 256, 0, stream>>>(cursor, bin, (const unsigned short*)ysb,
                                       M2, cvec, Wout, hr, hc, N);
    k_edge_add<<<eb, 256, 0, stream>>>(row, col, hr, hc, out, E);
}